// Round 3
// baseline (415.579 us; speedup 1.0000x reference)
//
#include <hip/hip_runtime.h>
#include <stdint.h>

#define B_   4
#define C_   256
#define W_   4096
#define DQK_ 32
#define NT_  128   // number of 32-wide n tiles

typedef short bf16x8 __attribute__((ext_vector_type(8)));
typedef float f32x4  __attribute__((ext_vector_type(4)));

__device__ __forceinline__ float fexp2f(float x){
#if __has_builtin(__builtin_amdgcn_exp2f)
  return __builtin_amdgcn_exp2f(x);
#else
  return exp2f(x);
#endif
}
__device__ __forceinline__ float frcpf(float x){
#if __has_builtin(__builtin_amdgcn_rcpf)
  return __builtin_amdgcn_rcpf(x);
#else
  return 1.0f / x;
#endif
}
__device__ __forceinline__ unsigned short bf16rn(float f){
  union { float f; uint32_t u; } v; v.f = f;
  uint32_t u = v.u;
  u += 0x7FFFu + ((u >> 16) & 1u);
  return (unsigned short)(u >> 16);
}

// ---------------------------------------------------------------------------
// K1: projections q = wq@x0+bq, k = (wk@x1+bk)*scale*log2e -> bf16 [B][W][32],
//     plus x0 -> bf16 in TILED layout x0t[b][w>>5][c][swz(w&31)] (16KB tiles,
//     XOR-swizzled within 64B rows so sa_pv's LDS reads are conflict-reduced).
// grid (64,4) block 256 (4 waves, c split 4x). c-loop NOT unrolled (R2 spill).
// ---------------------------------------------------------------------------
__global__ __launch_bounds__(256) void sa_prep(
    const float* __restrict__ x0, const float* __restrict__ x1,
    const float* __restrict__ wq, const float* __restrict__ bq,
    const float* __restrict__ wk, const float* __restrict__ bk,
    unsigned short* __restrict__ qT, unsigned short* __restrict__ kT,
    unsigned short* __restrict__ x0t)
{
  const int b    = blockIdx.y;
  const int lane = threadIdx.x & 63;
  const int cq   = threadIdx.x >> 6;           // 0..3
  const int w    = blockIdx.x * 64 + lane;
  const size_t bw = (size_t)b * ((size_t)C_ * W_) + w;
  const int wn = w & 31;
  unsigned short* xt = x0t + ((size_t)b * NT_ + (w >> 5)) * ((size_t)C_ * 32);

  float accq[DQK_], acck[DQK_];
  #pragma unroll
  for (int d = 0; d < DQK_; ++d){ accq[d] = 0.f; acck[d] = 0.f; }

  const int c0 = cq * 64;
  for (int i = 0; i < 64; ++i){
    const int c = c0 + i;
    const size_t off = bw + (size_t)c * W_;
    const float v0 = x0[off];
    const float v1 = x1[off];
    xt[(size_t)c * 32 + (((((unsigned)wn >> 3) ^ (c & 3)) << 3) | (wn & 7))] = bf16rn(v0);
    #pragma unroll
    for (int d = 0; d < DQK_; ++d){
      accq[d] = fmaf(wq[d * C_ + c], v0, accq[d]);
      acck[d] = fmaf(wk[d * C_ + c], v1, acck[d]);
    }
  }

  __shared__ float red[4][64][DQK_ + 1];
  #pragma unroll
  for (int d = 0; d < DQK_; ++d) red[cq][lane][d] = accq[d];
  __syncthreads();
  {
    const int d0 = cq * 8;       // each thread packs 8 d's for its own w
    uint32_t pk[4];
    #pragma unroll
    for (int jp = 0; jp < 4; ++jp){
      float s0 = bq[d0 + jp*2], s1 = bq[d0 + jp*2 + 1];
      #pragma unroll
      for (int w4 = 0; w4 < 4; ++w4){
        s0 += red[w4][lane][d0 + jp*2];
        s1 += red[w4][lane][d0 + jp*2 + 1];
      }
      pk[jp] = (uint32_t)bf16rn(s0) | ((uint32_t)bf16rn(s1) << 16);
    }
    *(uint4*)(qT + ((size_t)b * W_ + w) * DQK_ + d0) = make_uint4(pk[0],pk[1],pk[2],pk[3]);
  }
  __syncthreads();
  #pragma unroll
  for (int d = 0; d < DQK_; ++d) red[cq][lane][d] = acck[d];
  __syncthreads();
  {
    const float SCL = 0.0625f * 1.44269504088896340736f; // 1/sqrt(256)*log2(e)
    const int d0 = cq * 8;
    uint32_t pk[4];
    #pragma unroll
    for (int jp = 0; jp < 4; ++jp){
      float s0 = bk[d0 + jp*2], s1 = bk[d0 + jp*2 + 1];
      #pragma unroll
      for (int w4 = 0; w4 < 4; ++w4){
        s0 += red[w4][lane][d0 + jp*2];
        s1 += red[w4][lane][d0 + jp*2 + 1];
      }
      pk[jp] = (uint32_t)bf16rn(s0 * SCL) | ((uint32_t)bf16rn(s1 * SCL) << 16);
    }
    *(uint4*)(kT + ((size_t)b * W_ + w) * DQK_ + d0) = make_uint4(pk[0],pk[1],pk[2],pk[3]);
  }
}

// ---------------------------------------------------------------------------
// K2: denominators. Per (b, 16-row m-tile): 4 waves split n 4x1024, sum exp2,
// shfl+LDS combine, write invS[b][m]. grid 1024, block 256.
// ---------------------------------------------------------------------------
__global__ __launch_bounds__(256) void sa_denom(
    const unsigned short* __restrict__ qT, const unsigned short* __restrict__ kT,
    float* __restrict__ invS)
{
  const int lb = blockIdx.x;
  const int b = (lb & 7) >> 1;
  const int mtile = ((lb >> 3) << 1) | (lb & 1);     // 0..255
  const int lane = threadIdx.x & 63;
  const int wid = threadIdx.x >> 6;
  const int lr = lane & 15, lg = lane >> 4;
  const int m0 = mtile * 16;
  const int nbase = wid * 1024;

  const bf16x8 kfrag = *(const bf16x8*)(kT + ((size_t)b * W_ + m0 + lr) * DQK_ + (size_t)lg * 8);
  const unsigned short* qb = qT + (size_t)b * W_ * DQK_;

  float ps[4] = {0.f, 0.f, 0.f, 0.f};
  for (int i = 0; i < 32; ++i){
    const int n0 = nbase + i * 32;
    bf16x8 q0 = *(const bf16x8*)(qb + (size_t)(n0 + lr) * DQK_ + (size_t)lg * 8);
    bf16x8 q1 = *(const bf16x8*)(qb + (size_t)(n0 + 16 + lr) * DQK_ + (size_t)lg * 8);
    f32x4 e0 = __builtin_amdgcn_mfma_f32_16x16x32_bf16(kfrag, q0, (f32x4){0.f,0.f,0.f,0.f}, 0, 0, 0);
    f32x4 e1 = __builtin_amdgcn_mfma_f32_16x16x32_bf16(kfrag, q1, (f32x4){0.f,0.f,0.f,0.f}, 0, 0, 0);
    #pragma unroll
    for (int r = 0; r < 4; ++r) ps[r] += fexp2f(e0[r]) + fexp2f(e1[r]);
  }
  #pragma unroll
  for (int mask = 1; mask <= 8; mask <<= 1){
    #pragma unroll
    for (int r = 0; r < 4; ++r) ps[r] += __shfl_xor(ps[r], mask);
  }
  __shared__ float ssum[4][16];
  if (lr == 0){
    #pragma unroll
    for (int r = 0; r < 4; ++r) ssum[wid][lg * 4 + r] = ps[r];
  }
  __syncthreads();
  if (threadIdx.x < 16){
    float s = ssum[0][threadIdx.x] + ssum[1][threadIdx.x]
            + ssum[2][threadIdx.x] + ssum[3][threadIdx.x];
    invS[(size_t)b * W_ + m0 + threadIdx.x] = frcpf(s);
  }
}

// ---------------------------------------------------------------------------
// K3: attention write only. Wave = one m-16-tile x 1024-n-slice. No LDS.
// Pure coalesced f32 stores -> HBM-write bound. grid 1024, block 256.
// ---------------------------------------------------------------------------
__global__ __launch_bounds__(256) void sa_att(
    const unsigned short* __restrict__ qT, const unsigned short* __restrict__ kT,
    const float* __restrict__ invS, float* __restrict__ att)
{
  const int lb = blockIdx.x;
  const int b = (lb & 7) >> 1;
  const int id = ((lb >> 3) << 1) | (lb & 1);        // 0..255
  const int mgroup = id & 63, nslice = id >> 6;
  const int lane = threadIdx.x & 63;
  const int wid = threadIdx.x >> 6;
  const int lr = lane & 15, lg = lane >> 4;
  const int m0 = mgroup * 64 + wid * 16;
  const int nbase = nslice * 1024;

  const bf16x8 kfrag = *(const bf16x8*)(kT + ((size_t)b * W_ + m0 + lr) * DQK_ + (size_t)lg * 8);
  const unsigned short* qb = qT + (size_t)b * W_ * DQK_;
  const f32x4 inv4 = *(const f32x4*)(invS + (size_t)b * W_ + m0 + lg * 4);

  float* attb = att + ((size_t)b * W_ + m0) * W_;
  float* arow[4];
  #pragma unroll
  for (int r = 0; r < 4; ++r) arow[r] = attb + (size_t)(lg * 4 + r) * W_ + lr;

  for (int i = 0; i < 32; ++i){
    const int n0 = nbase + i * 32;
    bf16x8 q0 = *(const bf16x8*)(qb + (size_t)(n0 + lr) * DQK_ + (size_t)lg * 8);
    bf16x8 q1 = *(const bf16x8*)(qb + (size_t)(n0 + 16 + lr) * DQK_ + (size_t)lg * 8);
    f32x4 e0 = __builtin_amdgcn_mfma_f32_16x16x32_bf16(kfrag, q0, (f32x4){0.f,0.f,0.f,0.f}, 0, 0, 0);
    f32x4 e1 = __builtin_amdgcn_mfma_f32_16x16x32_bf16(kfrag, q1, (f32x4){0.f,0.f,0.f,0.f}, 0, 0, 0);
    #pragma unroll
    for (int r = 0; r < 4; ++r){
      arow[r][n0]      = fexp2f(e0[r]) * inv4[r];
      arow[r][n0 + 16] = fexp2f(e1[r]) * inv4[r];
    }
  }
}

// ---------------------------------------------------------------------------
// K4: PV GEMM out[b][c][m] = gamma * sum_n att[b][m][n]*x0[b][c][n] + x1.
// Block tile: 256c x 32m, K-loop over 128 tiles of 32n. A (x0t tile, 16KB
// contiguous, pre-swizzled) via global_load_lds; B (att f32 -> bf16) reg-
// staged into padded LDS. Double-buffered. grid 512, block 256 (4 waves).
// ---------------------------------------------------------------------------
__global__ __launch_bounds__(256) void sa_pv(
    const float* __restrict__ att, const unsigned short* __restrict__ x0t,
    const float* __restrict__ x1, const float* __restrict__ gamma,
    float* __restrict__ out)
{
  const int lb = blockIdx.x;
  const int b = (lb & 7) >> 1;
  const int mt = ((lb >> 3) << 1) | (lb & 1);        // 0..127
  const int m0 = mt * 32;
  const int tid = threadIdx.x;
  const int lane = tid & 63, wv = tid >> 6;
  const int lr = lane & 15, lg = lane >> 4;

  __shared__ __align__(16) unsigned short Abuf[2][C_ * 32];   // 16KB each, linear
  __shared__ __align__(16) unsigned short Bbuf[2][32 * 40];   // padded pitch 40

  const unsigned short* xtb = x0t + (size_t)b * NT_ * ((size_t)C_ * 32);
  const float* attb = att + ((size_t)b * W_ + m0) * W_;
  const int brow = tid >> 3, bcol = (tid & 7) * 4;

  f32x4 acc[4][2];
  #pragma unroll
  for (int a = 0; a < 4; ++a){ acc[a][0] = (f32x4){0.f,0.f,0.f,0.f}; acc[a][1] = (f32x4){0.f,0.f,0.f,0.f}; }

  #define STAGE(J, BUF) do {                                                    \
    const unsigned short* asrc = xtb + (size_t)(J) * (C_*32) + (wv*4)*512 + lane*8; \
    unsigned short* adst = &Abuf[BUF][(wv*4)*512];                              \
    _Pragma("unroll")                                                           \
    for (int k2 = 0; k2 < 4; ++k2){                                             \
      __builtin_amdgcn_global_load_lds(                                         \
        (const __attribute__((address_space(1))) unsigned int*)(asrc + k2*512), \
        (__attribute__((address_space(3))) unsigned int*)(adst + k2*512),       \
        16, 0, 0);                                                              \
    }                                                                           \
    f32x4 v = *(const f32x4*)(attb + (size_t)brow * W_ + (J)*32 + bcol);        \
    uint2 pk;                                                                   \
    pk.x = (uint32_t)bf16rn(v[0]) | ((uint32_t)bf16rn(v[1]) << 16);             \
    pk.y = (uint32_t)bf16rn(v[2]) | ((uint32_t)bf16rn(v[3]) << 16);             \
    *(uint2*)&Bbuf[BUF][brow * 40 + bcol] = pk;                                 \
  } while(0)

  STAGE(0, 0);
  __syncthreads();

  for (int nw = 0; nw < NT_; ++nw){
    const int cur = nw & 1;
    if (nw + 1 < NT_){ STAGE(nw + 1, cur ^ 1); }
    // B-frags: B[k=n][j=m] = att[m][n]; lane col j=lr -> m-local, k-slice lg*8
    bf16x8 bf0 = *(const bf16x8*)&Bbuf[cur][(size_t)lr * 40 + lg * 8];
    bf16x8 bf1 = *(const bf16x8*)&Bbuf[cur][(size_t)(16 + lr) * 40 + lg * 8];
    #pragma unroll
    for (int a = 0; a < 4; ++a){
      const int crow = wv * 64 + a * 16 + lr;
      bf16x8 af = *(const bf16x8*)&Abuf[cur][(size_t)crow * 32 + (((unsigned)lg ^ (crow & 3)) << 3)];
      acc[a][0] = __builtin_amdgcn_mfma_f32_16x16x32_bf16(af, bf0, acc[a][0], 0, 0, 0);
      acc[a][1] = __builtin_amdgcn_mfma_f32_16x16x32_bf16(af, bf1, acc[a][1], 0, 0, 0);
    }
    __syncthreads();
  }
  #undef STAGE

  const float g = gamma[0];
  const float* x1b = x1 + (size_t)b * C_ * W_;
  float* outb = out + (size_t)b * C_ * W_;
  #pragma unroll
  for (int a = 0; a < 4; ++a){
    #pragma unroll
    for (int mtl = 0; mtl < 2; ++mtl){
      #pragma unroll
      for (int r = 0; r < 4; ++r){
        const int c = wv * 64 + a * 16 + lg * 4 + r;
        const size_t idx = (size_t)c * W_ + m0 + mtl * 16 + lr;
        outb[idx] = fmaf(g, acc[a][mtl][r], x1b[idx]);
      }
    }
  }
}

extern "C" void kernel_launch(void* const* d_in, const int* in_sizes, int n_in,
                              void* d_out, int out_size, void* d_ws, size_t ws_size,
                              hipStream_t stream)
{
  (void)in_sizes; (void)n_in; (void)out_size; (void)ws_size;
  const float* x0    = (const float*)d_in[0];
  const float* x1    = (const float*)d_in[1];
  const float* wq    = (const float*)d_in[2];
  const float* bq    = (const float*)d_in[3];
  const float* wk    = (const float*)d_in[4];
  const float* bk    = (const float*)d_in[5];
  const float* gamma = (const float*)d_in[6];

  unsigned short* qT  = (unsigned short*)d_ws;                     // 1 MB
  unsigned short* kT  = qT + (size_t)B_ * W_ * DQK_;               // 1 MB
  unsigned short* x0t = kT + (size_t)B_ * W_ * DQK_;               // 8 MB tiled
  float*          invS = (float*)(x0t + (size_t)B_ * NT_ * C_ * 32); // 64 KB

  float* out = (float*)d_out;                                      // [B][C][W]
  float* att = out + (size_t)B_ * C_ * W_;                         // [B][W][W]

  sa_prep <<<dim3(64, 4), 256, 0, stream>>>(x0, x1, wq, bq, wk, bk, qT, kT, x0t);
  sa_denom<<<1024, 256, 0, stream>>>(qT, kT, invS);
  sa_att  <<<1024, 256, 0, stream>>>(qT, kT, invS, att);
  sa_pv   <<<512, 256, 0, stream>>>(att, x0t, x1, gamma, out);
}

// Round 4
// 387.624 us; speedup vs baseline: 1.0721x; 1.0721x over previous
//
#include <hip/hip_runtime.h>
#include <stdint.h>

#define B_   4
#define C_   256
#define W_   4096
#define DQK_ 32
#define NT_  128   // number of 32-wide n tiles

typedef short bf16x8 __attribute__((ext_vector_type(8)));
typedef float f32x4  __attribute__((ext_vector_type(4)));

__device__ __forceinline__ float fexp2f(float x){
#if __has_builtin(__builtin_amdgcn_exp2f)
  return __builtin_amdgcn_exp2f(x);
#else
  return exp2f(x);
#endif
}
__device__ __forceinline__ float frcpf(float x){
#if __has_builtin(__builtin_amdgcn_rcpf)
  return __builtin_amdgcn_rcpf(x);
#else
  return 1.0f / x;
#endif
}
__device__ __forceinline__ unsigned short bf16rn(float f){
  union { float f; uint32_t u; } v; v.f = f;
  uint32_t u = v.u;
  u += 0x7FFFu + ((u >> 16) & 1u);
  return (unsigned short)(u >> 16);
}
__device__ __forceinline__ uint32_t pk2(float a, float b){
  return (uint32_t)bf16rn(a) | ((uint32_t)bf16rn(b) << 16);
}

// ---------------------------------------------------------------------------
// K1: projections q = wq@x0+bq, k = (wk@x1+bk)*scale*log2e -> bf16 [B][W][32],
//     plus x0 -> bf16 in LINEAR TILED layout x0t[b][w>>5][c][w&31]
//     (16KB contiguous per 32-n tile -> global_load_lds friendly).
// grid (64,4) block 256 (4 waves, c split 4x). c-loop NOT unrolled (R2 spill).
// ---------------------------------------------------------------------------
__global__ __launch_bounds__(256) void sa_prep(
    const float* __restrict__ x0, const float* __restrict__ x1,
    const float* __restrict__ wq, const float* __restrict__ bq,
    const float* __restrict__ wk, const float* __restrict__ bk,
    unsigned short* __restrict__ qT, unsigned short* __restrict__ kT,
    unsigned short* __restrict__ x0t)
{
  const int b    = blockIdx.y;
  const int lane = threadIdx.x & 63;
  const int cq   = threadIdx.x >> 6;           // 0..3
  const int w    = blockIdx.x * 64 + lane;
  const size_t bw = (size_t)b * ((size_t)C_ * W_) + w;
  const int wn = w & 31;
  unsigned short* xt = x0t + ((size_t)b * NT_ + (w >> 5)) * ((size_t)C_ * 32);

  float accq[DQK_], acck[DQK_];
  #pragma unroll
  for (int d = 0; d < DQK_; ++d){ accq[d] = 0.f; acck[d] = 0.f; }

  const int c0 = cq * 64;
  for (int i = 0; i < 64; ++i){
    const int c = c0 + i;
    const size_t off = bw + (size_t)c * W_;
    const float v0 = x0[off];
    const float v1 = x1[off];
    xt[(size_t)c * 32 + wn] = bf16rn(v0);
    #pragma unroll
    for (int d = 0; d < DQK_; ++d){
      accq[d] = fmaf(wq[d * C_ + c], v0, accq[d]);
      acck[d] = fmaf(wk[d * C_ + c], v1, acck[d]);
    }
  }

  __shared__ float red[4][64][DQK_ + 1];
  #pragma unroll
  for (int d = 0; d < DQK_; ++d) red[cq][lane][d] = accq[d];
  __syncthreads();
  {
    const int d0 = cq * 8;       // each thread packs 8 d's for its own w
    uint32_t pk[4];
    #pragma unroll
    for (int jp = 0; jp < 4; ++jp){
      float s0 = bq[d0 + jp*2], s1 = bq[d0 + jp*2 + 1];
      #pragma unroll
      for (int w4 = 0; w4 < 4; ++w4){
        s0 += red[w4][lane][d0 + jp*2];
        s1 += red[w4][lane][d0 + jp*2 + 1];
      }
      pk[jp] = pk2(s0, s1);
    }
    *(uint4*)(qT + ((size_t)b * W_ + w) * DQK_ + d0) = make_uint4(pk[0],pk[1],pk[2],pk[3]);
  }
  __syncthreads();
  #pragma unroll
  for (int d = 0; d < DQK_; ++d) red[cq][lane][d] = acck[d];
  __syncthreads();
  {
    const float SCL = 0.0625f * 1.44269504088896340736f; // 1/sqrt(256)*log2(e)
    const int d0 = cq * 8;
    uint32_t pk[4];
    #pragma unroll
    for (int jp = 0; jp < 4; ++jp){
      float s0 = bk[d0 + jp*2], s1 = bk[d0 + jp*2 + 1];
      #pragma unroll
      for (int w4 = 0; w4 < 4; ++w4){
        s0 += red[w4][lane][d0 + jp*2];
        s1 += red[w4][lane][d0 + jp*2 + 1];
      }
      pk[jp] = pk2(s0 * SCL, s1 * SCL);
    }
    *(uint4*)(kT + ((size_t)b * W_ + w) * DQK_ + d0) = make_uint4(pk[0],pk[1],pk[2],pk[3]);
  }
}

// ---------------------------------------------------------------------------
// K2: denominators. Per (b, 16-row m-tile): 4 waves split n 4x1024, sum exp2,
// shfl+LDS combine, write invS[b][m]. grid 1024, block 256.
// ---------------------------------------------------------------------------
__global__ __launch_bounds__(256) void sa_denom(
    const unsigned short* __restrict__ qT, const unsigned short* __restrict__ kT,
    float* __restrict__ invS)
{
  const int lb = blockIdx.x;
  const int b = (lb & 7) >> 1;
  const int mtile = ((lb >> 3) << 1) | (lb & 1);     // 0..255
  const int lane = threadIdx.x & 63;
  const int wid = threadIdx.x >> 6;
  const int lr = lane & 15, lg = lane >> 4;
  const int m0 = mtile * 16;
  const int nbase = wid * 1024;

  const bf16x8 kfrag = *(const bf16x8*)(kT + ((size_t)b * W_ + m0 + lr) * DQK_ + (size_t)lg * 8);
  const unsigned short* qb = qT + (size_t)b * W_ * DQK_;

  float ps[4] = {0.f, 0.f, 0.f, 0.f};
  for (int i = 0; i < 32; ++i){
    const int n0 = nbase + i * 32;
    bf16x8 q0 = *(const bf16x8*)(qb + (size_t)(n0 + lr) * DQK_ + (size_t)lg * 8);
    bf16x8 q1 = *(const bf16x8*)(qb + (size_t)(n0 + 16 + lr) * DQK_ + (size_t)lg * 8);
    f32x4 e0 = __builtin_amdgcn_mfma_f32_16x16x32_bf16(kfrag, q0, (f32x4){0.f,0.f,0.f,0.f}, 0, 0, 0);
    f32x4 e1 = __builtin_amdgcn_mfma_f32_16x16x32_bf16(kfrag, q1, (f32x4){0.f,0.f,0.f,0.f}, 0, 0, 0);
    #pragma unroll
    for (int r = 0; r < 4; ++r) ps[r] += fexp2f(e0[r]) + fexp2f(e1[r]);
  }
  #pragma unroll
  for (int mask = 1; mask <= 8; mask <<= 1){
    #pragma unroll
    for (int r = 0; r < 4; ++r) ps[r] += __shfl_xor(ps[r], mask);
  }
  __shared__ float ssum[4][16];
  if (lr == 0){
    #pragma unroll
    for (int r = 0; r < 4; ++r) ssum[wid][lg * 4 + r] = ps[r];
  }
  __syncthreads();
  if (threadIdx.x < 16){
    float s = ssum[0][threadIdx.x] + ssum[1][threadIdx.x]
            + ssum[2][threadIdx.x] + ssum[3][threadIdx.x];
    invS[(size_t)b * W_ + m0 + threadIdx.x] = frcpf(s);
  }
}

// ---------------------------------------------------------------------------
// K3: fused attention-write + PV + epilogue.
// Block: (b, m-32 tile), 4 waves split c 4x64. Sweep all n in 128 steps of 32.
// Per step: double-buffered x0t tile (16KB) via global_load_lds; energy
// TRANSPOSED e' = mfma(q,k) so P is lane-local with m=lane&15 and r = consec n
// -> f32x4 contiguous att stores + uint2-packed P into per-wave LDS ->
// ds_read_b128 B-frags for PV MFMA. Epilogue: out = gamma*acc + x1.
// grid 512 (XCD-paired per batch), block 256.
// ---------------------------------------------------------------------------
__global__ __launch_bounds__(256) void sa_fused(
    const unsigned short* __restrict__ qT, const unsigned short* __restrict__ kT,
    const unsigned short* __restrict__ x0t, const float* __restrict__ x1,
    const float* __restrict__ invS, const float* __restrict__ gamma,
    float* __restrict__ out, float* __restrict__ att)
{
  const int lb = blockIdx.x;
  const int b    = (lb & 7) >> 1;                    // batch -> XCD pair
  const int mloc = ((lb >> 3) << 1) | (lb & 1);      // 0..127
  const int m0 = mloc * 32;
  const int lane = threadIdx.x & 63;
  const int wid = threadIdx.x >> 6;                  // c-split 0..3, att quarter
  const int lr = lane & 15, lg = lane >> 4;

  __shared__ __align__(16) unsigned short Abuf[2][8192];    // [256c][32n] 16KB x2
  __shared__ __align__(16) unsigned short Plds[4][32 * 32]; // per-wave [32m][32n]

  // hoisted per-mt K fragments (B-operand cols = m) and denominators
  const unsigned short* kb = kT + ((size_t)b * W_ + m0) * DQK_;
  const bf16x8 kf0 = *(const bf16x8*)(kb + (size_t)lr * DQK_ + lg * 8);
  const bf16x8 kf1 = *(const bf16x8*)(kb + (size_t)(16 + lr) * DQK_ + lg * 8);
  const float is0 = invS[(size_t)b * W_ + m0 + lr];
  const float is1 = invS[(size_t)b * W_ + m0 + 16 + lr];
  const unsigned short* qb = qT + (size_t)b * W_ * DQK_;
  const unsigned short* xtb = x0t + (size_t)b * NT_ * 8192;

  f32x4 acc[4][2];
  #pragma unroll
  for (int ct = 0; ct < 4; ++ct){
    acc[ct][0] = (f32x4){0.f,0.f,0.f,0.f};
    acc[ct][1] = (f32x4){0.f,0.f,0.f,0.f};
  }

  unsigned short* pl = &Plds[wid][0];
  const int mta = wid >> 1, nta = wid & 1;           // this wave's att quarter
  float* attq = att + ((size_t)b * W_ + m0 + mta * 16 + lr) * W_ + nta * 16 + lg * 4;

  #define STAGE(J, BUF) do {                                                      \
    const unsigned short* src_ = xtb + (size_t)(J) * 8192 + wid * 2048 + lane * 8;\
    unsigned short* dst_ = &Abuf[BUF][wid * 2048];                                \
    _Pragma("unroll")                                                             \
    for (int k2 = 0; k2 < 4; ++k2){                                               \
      __builtin_amdgcn_global_load_lds(                                           \
        (const __attribute__((address_space(1))) unsigned int*)(src_ + k2*512),   \
        (__attribute__((address_space(3))) unsigned int*)(dst_ + k2*512),         \
        16, 0, 0);                                                                \
    }                                                                             \
  } while(0)

  STAGE(0, 0);
  __syncthreads();

  for (int s = 0; s < NT_; ++s){
    const int cur = s & 1;
    if (s + 1 < NT_){ STAGE(s + 1, cur ^ 1); }
    const int n0 = s * 32;

    // ---- energy (transposed): e[nt][mt], D rows = n, cols = m ----
    bf16x8 qf0 = *(const bf16x8*)(qb + (size_t)(n0 + lr) * DQK_ + (size_t)lg * 8);
    bf16x8 qf1 = *(const bf16x8*)(qb + (size_t)(n0 + 16 + lr) * DQK_ + (size_t)lg * 8);
    f32x4 e00 = __builtin_amdgcn_mfma_f32_16x16x32_bf16(qf0, kf0, (f32x4){0.f,0.f,0.f,0.f}, 0, 0, 0);
    f32x4 e01 = __builtin_amdgcn_mfma_f32_16x16x32_bf16(qf0, kf1, (f32x4){0.f,0.f,0.f,0.f}, 0, 0, 0);
    f32x4 e10 = __builtin_amdgcn_mfma_f32_16x16x32_bf16(qf1, kf0, (f32x4){0.f,0.f,0.f,0.f}, 0, 0, 0);
    f32x4 e11 = __builtin_amdgcn_mfma_f32_16x16x32_bf16(qf1, kf1, (f32x4){0.f,0.f,0.f,0.f}, 0, 0, 0);

    f32x4 p00, p01, p10, p11;
    #pragma unroll
    for (int r = 0; r < 4; ++r){
      p00[r] = fexp2f(e00[r]) * is0;   // nt0, mt0
      p01[r] = fexp2f(e01[r]) * is1;   // nt0, mt1
      p10[r] = fexp2f(e10[r]) * is0;   // nt1, mt0
      p11[r] = fexp2f(e11[r]) * is1;   // nt1, mt1
    }

    // ---- att store: this wave's quarter, 16B contiguous per lane ----
    {
      f32x4 psel = (wid == 0) ? p00 : (wid == 1) ? p10 : (wid == 2) ? p01 : p11;
      *(f32x4*)(attq + n0) = psel;
    }

    // ---- P pack into per-wave LDS [32m][32n] (bf16) ----
    {
      uint2 v;
      v.x = pk2(p00[0], p00[1]); v.y = pk2(p00[2], p00[3]);
      *(uint2*)(pl + (size_t)lr * 32 + lg * 4) = v;                  // mt0 nt0
      v.x = pk2(p10[0], p10[1]); v.y = pk2(p10[2], p10[3]);
      *(uint2*)(pl + (size_t)lr * 32 + 16 + lg * 4) = v;             // mt0 nt1
      v.x = pk2(p01[0], p01[1]); v.y = pk2(p01[2], p01[3]);
      *(uint2*)(pl + (size_t)(16 + lr) * 32 + lg * 4) = v;           // mt1 nt0
      v.x = pk2(p11[0], p11[1]); v.y = pk2(p11[2], p11[3]);
      *(uint2*)(pl + (size_t)(16 + lr) * 32 + 16 + lg * 4) = v;      // mt1 nt1
    }

    // ---- PV: A = x0 tile rows c (LDS), B = P (per-wave LDS) ----
    bf16x8 pf0 = *(const bf16x8*)(pl + (size_t)lr * 32 + lg * 8);
    bf16x8 pf1 = *(const bf16x8*)(pl + (size_t)(16 + lr) * 32 + lg * 8);
    #pragma unroll
    for (int ct = 0; ct < 4; ++ct){
      bf16x8 af = *(const bf16x8*)(&Abuf[cur][(size_t)(wid * 64 + ct * 16 + lr) * 32 + lg * 8]);
      acc[ct][0] = __builtin_amdgcn_mfma_f32_16x16x32_bf16(af, pf0, acc[ct][0], 0, 0, 0);
      acc[ct][1] = __builtin_amdgcn_mfma_f32_16x16x32_bf16(af, pf1, acc[ct][1], 0, 0, 0);
    }
    __syncthreads();
  }
  #undef STAGE

  // ---- epilogue: out[c][m] = gamma*acc + x1 ----
  const float g = gamma[0];
  const float* x1b = x1 + (size_t)b * C_ * W_;
  float* outb = out + (size_t)b * C_ * W_;
  #pragma unroll
  for (int ct = 0; ct < 4; ++ct){
    #pragma unroll
    for (int mt = 0; mt < 2; ++mt){
      #pragma unroll
      for (int r = 0; r < 4; ++r){
        const int c = wid * 64 + ct * 16 + lg * 4 + r;
        const size_t idx = (size_t)c * W_ + m0 + mt * 16 + lr;
        outb[idx] = fmaf(g, acc[ct][mt][r], x1b[idx]);
      }
    }
  }
}

extern "C" void kernel_launch(void* const* d_in, const int* in_sizes, int n_in,
                              void* d_out, int out_size, void* d_ws, size_t ws_size,
                              hipStream_t stream)
{
  (void)in_sizes; (void)n_in; (void)out_size; (void)ws_size;
  const float* x0    = (const float*)d_in[0];
  const float* x1    = (const float*)d_in[1];
  const float* wq    = (const float*)d_in[2];
  const float* bq    = (const float*)d_in[3];
  const float* wk    = (const float*)d_in[4];
  const float* bk    = (const float*)d_in[5];
  const float* gamma = (const float*)d_in[6];

  unsigned short* qT  = (unsigned short*)d_ws;                       // 1 MB
  unsigned short* kT  = qT + (size_t)B_ * W_ * DQK_;                 // 1 MB
  unsigned short* x0t = kT + (size_t)B_ * W_ * DQK_;                 // 8 MB tiled
  float*          invS = (float*)(x0t + (size_t)B_ * NT_ * C_ * 32); // 64 KB

  float* out = (float*)d_out;                                        // [B][C][W]
  float* att = out + (size_t)B_ * C_ * W_;                           // [B][W][W]

  sa_prep <<<dim3(64, 4), 256, 0, stream>>>(x0, x1, wq, bq, wk, bk, qT, kT, x0t);
  sa_denom<<<1024, 256, 0, stream>>>(qT, kT, invS);
  sa_fused<<<512, 256, 0, stream>>>(qT, kT, x0t, x1, invS, gamma, out, att);
}

// Round 5
// 167.354 us; speedup vs baseline: 2.4832x; 2.3162x over previous
//
#include <hip/hip_runtime.h>
#include <stdint.h>

#define B_    4
#define C_    256
#define W_    4096
#define DQK_  32
#define NT64_ 64      // 64-wide n tiles per batch
#define TSZ_  16384   // shorts per x0t tile (256c x 64n)

typedef short bf16x8 __attribute__((ext_vector_type(8)));
typedef float f32x4  __attribute__((ext_vector_type(4)));

__device__ __forceinline__ float fexp2f(float x){
#if __has_builtin(__builtin_amdgcn_exp2f)
  return __builtin_amdgcn_exp2f(x);
#else
  return exp2f(x);
#endif
}
__device__ __forceinline__ float frcpf(float x){
#if __has_builtin(__builtin_amdgcn_rcpf)
  return __builtin_amdgcn_rcpf(x);
#else
  return 1.0f / x;
#endif
}
__device__ __forceinline__ unsigned short bf16rn(float f){
  union { float f; uint32_t u; } v; v.f = f;
  uint32_t u = v.u;
  u += 0x7FFFu + ((u >> 16) & 1u);
  return (unsigned short)(u >> 16);
}
__device__ __forceinline__ uint32_t pk2(float a, float b){
  return (uint32_t)bf16rn(a) | ((uint32_t)bf16rn(b) << 16);
}

// ---------------------------------------------------------------------------
// K1: projections q = wq@x0+bq, k = (wk@x1+bk)*scale*log2e -> bf16 [B][W][32],
//     plus x0 -> bf16 into SWIZZLED tiled layout:
//     x0t tile (b, n>>6): short idx = c*64 + ((nn>>3)^(c&7))*8 + (nn&7), nn=n&63.
//     (pre-swizzled global source so sa_fused can global_load_lds linearly and
//      ds_read_b128 conflict-free — G21 both-sides rule.)
// grid (128,4), block 512 = 8 waves; wave cq: 32 w x 2-way c-split in-wave.
// ---------------------------------------------------------------------------
__global__ __launch_bounds__(512) void sa_prep(
    const float* __restrict__ x0, const float* __restrict__ x1,
    const float* __restrict__ wq, const float* __restrict__ bq,
    const float* __restrict__ wk, const float* __restrict__ bk,
    unsigned short* __restrict__ qT, unsigned short* __restrict__ kT,
    unsigned short* __restrict__ x0t)
{
  const int b     = blockIdx.y;
  const int tid   = threadIdx.x;
  const int lane  = tid & 63;
  const int cq    = tid >> 6;            // 0..7
  const int wloc  = lane & 31;
  const int chalf = lane >> 5;           // 0..1
  const int w     = blockIdx.x * 32 + wloc;
  const int c0    = cq * 32 + chalf * 16;
  const size_t bw = (size_t)b * ((size_t)C_ * W_) + w;
  const int nn    = w & 63;
  unsigned short* xt = x0t + (size_t)(b * NT64_ + (w >> 6)) * TSZ_;

  float accq[DQK_], acck[DQK_];
  #pragma unroll
  for (int d = 0; d < DQK_; ++d){ accq[d] = 0.f; acck[d] = 0.f; }

  for (int i = 0; i < 16; ++i){
    const int c = c0 + i;
    const size_t off = bw + (size_t)c * W_;
    const float v0 = x0[off];
    const float v1 = x1[off];
    xt[c * 64 + ((((unsigned)nn >> 3) ^ (c & 7)) << 3) + (nn & 7)] = bf16rn(v0);
    #pragma unroll
    for (int d = 0; d < DQK_; ++d){
      accq[d] = fmaf(wq[d * C_ + c], v0, accq[d]);
      acck[d] = fmaf(wk[d * C_ + c], v1, acck[d]);
    }
  }
  // combine the 2 in-wave c-halves
  #pragma unroll
  for (int d = 0; d < DQK_; ++d){
    accq[d] += __shfl_xor(accq[d], 32);
    acck[d] += __shfl_xor(acck[d], 32);
  }

  __shared__ float red[8][32][36];   // pitch 36 floats: 16B-aligned rows
  if (chalf == 0){
    #pragma unroll
    for (int d4 = 0; d4 < 8; ++d4){
      f32x4 t = { accq[d4*4], accq[d4*4+1], accq[d4*4+2], accq[d4*4+3] };
      *(f32x4*)&red[cq][wloc][d4 * 4] = t;
    }
  }
  __syncthreads();
  if (chalf == 0){
    const int d0 = cq * 4;
    float s[4];
    #pragma unroll
    for (int j = 0; j < 4; ++j){
      float t = bq[d0 + j];
      #pragma unroll
      for (int g = 0; g < 8; ++g) t += red[g][wloc][d0 + j];
      s[j] = t;
    }
    uint2 pk; pk.x = pk2(s[0], s[1]); pk.y = pk2(s[2], s[3]);
    *(uint2*)(qT + ((size_t)b * W_ + w) * DQK_ + d0) = pk;
  }
  __syncthreads();
  if (chalf == 0){
    #pragma unroll
    for (int d4 = 0; d4 < 8; ++d4){
      f32x4 t = { acck[d4*4], acck[d4*4+1], acck[d4*4+2], acck[d4*4+3] };
      *(f32x4*)&red[cq][wloc][d4 * 4] = t;
    }
  }
  __syncthreads();
  if (chalf == 0){
    const float SCL = 0.0625f * 1.44269504088896340736f; // 1/sqrt(256)*log2(e)
    const int d0 = cq * 4;
    float s[4];
    #pragma unroll
    for (int j = 0; j < 4; ++j){
      float t = bk[d0 + j];
      #pragma unroll
      for (int g = 0; g < 8; ++g) t += red[g][wloc][d0 + j];
      s[j] = t * SCL;
    }
    uint2 pk; pk.x = pk2(s[0], s[1]); pk.y = pk2(s[2], s[3]);
    *(uint2*)(kT + ((size_t)b * W_ + w) * DQK_ + d0) = pk;
  }
}

// ---------------------------------------------------------------------------
// K2: fused denom + attention-write + PV + epilogue.
// Block (b, m-32 tile), 512 thr = 8 waves; wave wid -> (nq=wid>>1, mt=wid&1):
// owns energy quarter [16n x 16m]. Pass1: energy-only sweep -> invS in-reg.
// Pass2 (64 iters of 64-n): 1 energy MFMA/wave -> exp2 -> P(shared 4KB LDS,
// XOR-swizzled) + f32x4 att store; x0t tile (32KB, double-buffered,
// global_load_lds of pre-swizzled source); PV: 8 MFMA/wave on 32 c-rows.
// 2 barriers/iter; single P buffer is safe (write<bar1<read<bar2<next write).
// grid 512 (XCD-paired per batch), LDS ~70KB -> 2 blocks/CU (16 waves/CU).
// ---------------------------------------------------------------------------
__global__ __launch_bounds__(512, 4) void sa_fused(
    const unsigned short* __restrict__ qT, const unsigned short* __restrict__ kT,
    const unsigned short* __restrict__ x0t, const float* __restrict__ x1,
    const float* __restrict__ gamma,
    float* __restrict__ out, float* __restrict__ att)
{
  const int lb = blockIdx.x;
  const int b    = (lb & 7) >> 1;                    // batch -> XCD pair
  const int mblk = ((lb >> 3) << 1) | (lb & 1);      // 0..127
  const int m0 = mblk * 32;
  const int tid = threadIdx.x;
  const int lane = tid & 63;
  const int wid = tid >> 6;                          // 0..7
  const int lr = lane & 15, lg = lane >> 4;
  const int mt = wid & 1, nq = wid >> 1;

  __shared__ __align__(16) unsigned short Abuf[2][TSZ_];  // 2 x 32KB, linear
  __shared__ __align__(16) unsigned short Plds[32 * 64];  // 4KB, XOR-swizzled
  __shared__ float ssum[8][16];

  const bf16x8 kf = *(const bf16x8*)(kT + ((size_t)b * W_ + m0 + mt * 16 + lr) * DQK_ + lg * 8);
  const unsigned short* qb  = qT + (size_t)b * W_ * DQK_;
  const unsigned short* xtb = x0t + (size_t)b * NT64_ * TSZ_;

  #define STAGE(J, BUF) do {                                                      \
    const unsigned short* src_ = xtb + (size_t)(J) * TSZ_ + wid * 2048 + lane * 8;\
    _Pragma("unroll")                                                             \
    for (int k2 = 0; k2 < 4; ++k2){                                               \
      __builtin_amdgcn_global_load_lds(                                           \
        (const __attribute__((address_space(1))) unsigned int*)(src_ + k2 * 512), \
        (__attribute__((address_space(3))) unsigned int*)(&Abuf[BUF][wid * 2048 + k2 * 512]), \
        16, 0, 0);                                                                \
    }                                                                             \
  } while(0)

  STAGE(0, 0);   // arrives during pass 1; drained at the ssum barrier

  // ---- pass 1: denominators (energy-only, this wave's n-quarter) ----
  float ps = 0.f;
  for (int s = 0; s < NT64_; ++s){
    bf16x8 qf = *(const bf16x8*)(qb + (size_t)(s * 64 + nq * 16 + lr) * DQK_ + lg * 8);
    f32x4 e = __builtin_amdgcn_mfma_f32_16x16x32_bf16(qf, kf, (f32x4){0.f,0.f,0.f,0.f}, 0, 0, 0);
    ps += fexp2f(e[0]) + fexp2f(e[1]) + fexp2f(e[2]) + fexp2f(e[3]);
  }
  ps += __shfl_xor(ps, 16);
  ps += __shfl_xor(ps, 32);
  if (lane < 16) ssum[wid][lane] = ps;     // lanes 0..15: lg==0, lr==lane
  __syncthreads();
  const float is = frcpf(ssum[mt][lr] + ssum[mt + 2][lr] + ssum[mt + 4][lr] + ssum[mt + 6][lr]);

  // ---- pass 2 ----
  f32x4 acc[2][2];
  #pragma unroll
  for (int ct = 0; ct < 2; ++ct)
    #pragma unroll
    for (int m2 = 0; m2 < 2; ++m2) acc[ct][m2] = (f32x4){0.f,0.f,0.f,0.f};

  const int mlocP = mt * 16 + lr;
  unsigned short* pwaddr = Plds + mlocP * 64
      + (((nq * 2 + (lg >> 1)) ^ (mlocP & 7)) << 3) + (lg & 1) * 4;
  float* attp = att + ((size_t)b * W_ + m0 + mt * 16 + lr) * W_ + nq * 16 + lg * 4;

  for (int s = 0; s < NT64_; ++s){
    const int cur = s & 1;
    const int n0 = s * 64;

    // energy quarter -> P
    bf16x8 qf = *(const bf16x8*)(qb + (size_t)(n0 + nq * 16 + lr) * DQK_ + lg * 8);
    f32x4 e = __builtin_amdgcn_mfma_f32_16x16x32_bf16(qf, kf, (f32x4){0.f,0.f,0.f,0.f}, 0, 0, 0);
    f32x4 p;
    #pragma unroll
    for (int r = 0; r < 4; ++r) p[r] = fexp2f(e[r]) * is;
    uint2 pv; pv.x = pk2(p[0], p[1]); pv.y = pk2(p[2], p[3]);
    *(uint2*)pwaddr = pv;

    __syncthreads();   // barrier 1: P visible; Abuf[cur] complete (prev iter's stage)

    *(f32x4*)(attp + n0) = p;                 // drained at barrier 2
    if (s + 1 < NT64_) STAGE(s + 1, cur ^ 1); // latency hidden under PV

    // PV: A = x0 rows c (swizzled Abuf), B = P (swizzled Plds)
    bf16x8 pf[2][2], af[2][2];
    #pragma unroll
    for (int m2 = 0; m2 < 2; ++m2){
      const int prow = m2 * 16 + lr;
      #pragma unroll
      for (int ks = 0; ks < 2; ++ks)
        pf[m2][ks] = *(const bf16x8*)&Plds[prow * 64 + (((ks * 4 + lg) ^ (prow & 7)) << 3)];
    }
    #pragma unroll
    for (int ct = 0; ct < 2; ++ct){
      const int crow = wid * 32 + ct * 16 + lr;
      #pragma unroll
      for (int ks = 0; ks < 2; ++ks)
        af[ct][ks] = *(const bf16x8*)&Abuf[cur][crow * 64 + (((ks * 4 + lg) ^ (crow & 7)) << 3)];
    }
    #pragma unroll
    for (int ct = 0; ct < 2; ++ct)
      #pragma unroll
      for (int m2 = 0; m2 < 2; ++m2){
        acc[ct][m2] = __builtin_amdgcn_mfma_f32_16x16x32_bf16(af[ct][0], pf[m2][0], acc[ct][m2], 0, 0, 0);
        acc[ct][m2] = __builtin_amdgcn_mfma_f32_16x16x32_bf16(af[ct][1], pf[m2][1], acc[ct][m2], 0, 0, 0);
      }

    __syncthreads();   // barrier 2: PV done (P + Abuf[cur^1] reusable), stage drained
  }
  #undef STAGE

  // ---- epilogue: out[c][m] = gamma*acc + x1 ----
  const float g = gamma[0];
  const float* x1b = x1 + (size_t)b * C_ * W_;
  float* outb = out + (size_t)b * C_ * W_;
  #pragma unroll
  for (int ct = 0; ct < 2; ++ct)
    #pragma unroll
    for (int m2 = 0; m2 < 2; ++m2)
      #pragma unroll
      for (int r = 0; r < 4; ++r){
        const int c = wid * 32 + ct * 16 + lg * 4 + r;
        const size_t idx = (size_t)c * W_ + m0 + m2 * 16 + lr;
        outb[idx] = fmaf(g, acc[ct][m2][r], x1b[idx]);
      }
}

extern "C" void kernel_launch(void* const* d_in, const int* in_sizes, int n_in,
                              void* d_out, int out_size, void* d_ws, size_t ws_size,
                              hipStream_t stream)
{
  (void)in_sizes; (void)n_in; (void)out_size; (void)ws_size;
  const float* x0    = (const float*)d_in[0];
  const float* x1    = (const float*)d_in[1];
  const float* wq    = (const float*)d_in[2];
  const float* bq    = (const float*)d_in[3];
  const float* wk    = (const float*)d_in[4];
  const float* bk    = (const float*)d_in[5];
  const float* gamma = (const float*)d_in[6];

  unsigned short* qT  = (unsigned short*)d_ws;                   // 1 MB
  unsigned short* kT  = qT + (size_t)B_ * W_ * DQK_;             // 1 MB
  unsigned short* x0t = kT + (size_t)B_ * W_ * DQK_;             // 8 MB swizzled tiles

  float* out = (float*)d_out;                                    // [B][C][W]
  float* att = out + (size_t)B_ * C_ * W_;                       // [B][W][W]

  sa_prep <<<dim3(128, 4), 512, 0, stream>>>(x0, x1, wq, bq, wk, bk, qT, kT, x0t);
  sa_fused<<<512, 512, 0, stream>>>(qT, kT, x0t, x1, gamma, out, att);
}